// Round 5
// baseline (672.145 us; speedup 1.0000x reference)
//
#include <hip/hip_runtime.h>
#include <stdint.h>

#define HW 4096
#define CH 384
#define NB 8
#define K_SEL 128
#define BIG_DIST 1.0e7f
#define BIG_DIFF 10000.0f

#define PAGE 16384         // one 256x32 f16 page (pre-swizzled in global)
#define NKB 12             // 384 / 32
#define NPAN 16            // 4096 / 256
#define NSTEP 36           // 3 sweeps x 12 K-steps

typedef unsigned long long u64;
typedef _Float16 f16;
typedef _Float16 f16x8 __attribute__((ext_vector_type(8)));
typedef float f32x4 __attribute__((ext_vector_type(4)));

__device__ __forceinline__ u64 encode_di(float d, int idx) {
    // d >= 0 always, so float bits are order-isomorphic.
    return ((u64)__float_as_uint(d) << 32) | (unsigned)idx;
}

__device__ __forceinline__ void gl_lds16(const void* g, void* l) {
    __builtin_amdgcn_global_load_lds(
        (const __attribute__((address_space(1))) unsigned int*)g,
        (__attribute__((address_space(3))) unsigned int*)l, 16, 0, 0);
}

__device__ __forceinline__ u64 min_shfl(u64 v, int mask) {
    u64 o = __shfl_xor(v, mask, 64);
    return o < v ? o : v;
}

// XOR swizzle inside one 256x32 f16 page (64B rows): rows 0..7 of a 16-row
// fragment group cover all 32 banks; rows 8..15 alias 2-way (free).
__device__ __forceinline__ int swz(int row, int bytecol) {
    return (row * 64 + bytecol) ^ ((row & 7) << 4);
}

#define BAR() do { asm volatile("" ::: "memory"); \
                   __builtin_amdgcn_s_barrier();  \
                   asm volatile("" ::: "memory"); } while (0)

// ---------------------------------------------------------------- init slots
__global__ void init_slots(u64* s, int n) {
    int i = blockIdx.x * blockDim.x + threadIdx.x;
    if (i < n) s[i] = ~0ULL;
}

// ------------------------------------------------------- row norms + sq sums
__global__ void normalize_rows(const float* __restrict__ f1,
                               const float* __restrict__ f2,
                               const int* __restrict__ mask1,
                               const int* __restrict__ mask2,
                               float* __restrict__ rn1, float* __restrict__ rn2,
                               float* __restrict__ sq1, float* __restrict__ sq2) {
    int gw = (blockIdx.x * blockDim.x + threadIdx.x) >> 6;
    int lane = threadIdx.x & 63;
    int which = gw >> 15;
    int row = gw & 32767;
    const float* f = which ? f2 : f1;
    const int* m = which ? mask2 : mask1;
    float* rn = which ? rn2 : rn1;
    float* sq = which ? sq2 : sq1;

    const float* p = f + (size_t)row * CH;
    float x[6];
    float s = 0.f;
#pragma unroll
    for (int t = 0; t < 6; ++t) { x[t] = p[lane + 64 * t]; s += x[t] * x[t]; }
#pragma unroll
    for (int off = 32; off >= 1; off >>= 1) s += __shfl_xor(s, off, 64);
    float r = 1.0f / __fsqrt_rn(s);
    float s2 = 0.f;
#pragma unroll
    for (int t = 0; t < 6; ++t) { float y = x[t] * r; s2 += y * y; }
#pragma unroll
    for (int off = 32; off >= 1; off >>= 1) s2 += __shfl_xor(s2, off, 64);
    if (lane == 0) {
        rn[row] = r;
        sq[row] = (m[row] > 0) ? s2 : 0.0f;
    }
}

// ------------- split f32 -> (hi f16, lo f16 * 2048), pre-tiled + pre-swizzled
// page lin = (b*NPAN + panel)*NKB + kb ; element (r,c) at byte swz(r, c*2)
__global__ __launch_bounds__(256)
void convert_tiles(const float* __restrict__ f1, const float* __restrict__ f2,
                   const float* __restrict__ rn1, const float* __restrict__ rn2,
                   char* __restrict__ tAhi, char* __restrict__ tAlo,
                   char* __restrict__ tBhi, char* __restrict__ tBlo) {
    int lin = blockIdx.x;
    int kb = lin % NKB;
    int pan = (lin / NKB) % NPAN;
    int b = lin / (NKB * NPAN);
    const float* f = blockIdx.y ? f2 : f1;
    const float* rn = blockIdx.y ? rn2 : rn1;
    char* hp = (blockIdx.y ? tBhi : tAhi) + (size_t)lin * PAGE;
    char* lp = (blockIdx.y ? tBlo : tAlo) + (size_t)lin * PAGE;
    int rowbase = pan * 256;

#pragma unroll
    for (int p = 0; p < 8; ++p) {
        int q = p * 256 + threadIdx.x;    // 0..2047
        int r = q >> 3;                   // local row 0..255
        int c4 = q & 7;                   // which float4 of the 32 k
        int grow = rowbase + r;
        float rv = rn[b * HW + grow];
        float4 x = *(const float4*)(f + ((size_t)b * HW + grow) * CH + kb * 32 + c4 * 4);
        x.x *= rv; x.y *= rv; x.z *= rv; x.w *= rv;
        f16 h0 = (f16)x.x, h1 = (f16)x.y, h2 = (f16)x.z, h3 = (f16)x.w;
        f16 l0 = (f16)((x.x - (float)h0) * 2048.0f);
        f16 l1 = (f16)((x.y - (float)h1) * 2048.0f);
        f16 l2 = (f16)((x.z - (float)h2) * 2048.0f);
        f16 l3 = (f16)((x.w - (float)h3) * 2048.0f);
        int off = (r * 64 + c4 * 8) ^ ((r & 7) << 4);
        union { f16 h[4]; uint2 u; } H = {{h0, h1, h2, h3}};
        union { f16 h[4]; uint2 u; } L = {{l0, l1, l2, l3}};
        *(uint2*)(hp + off) = H.u;
        *(uint2*)(lp + off) = L.u;
    }
}

// --------------------- 256^2 tri-buffered phase-interleaved GEMM + argmin
// 3 sweeps into ONE accumulator: lo.hi, hi.lo (both x2048), rescale, hi.hi.
__global__ __launch_bounds__(512, 2)
void gemm_argmin(const char* __restrict__ tAhi, const char* __restrict__ tAlo,
                 const char* __restrict__ tBhi, const char* __restrict__ tBlo,
                 const int* __restrict__ mask1, const int* __restrict__ mask2,
                 const float* __restrict__ sq1, const float* __restrict__ sq2,
                 u64* __restrict__ slot1, u64* __restrict__ slot2) {
    __shared__ __align__(16) char smem[3 * 2 * PAGE];   // 3 bufs x (A+B page)
    __shared__ u64 rowSlot[256];
    __shared__ u64 colSlot[256];

    const int b = blockIdx.y;
    const int tid = threadIdx.x;

    // XCD swizzle: xcd = x&7 (grid.x=256, 2048 blocks, %8 stable across y);
    // each XCD gets 2 consecutive row-panels of its batch -> A panel L2-hot.
    int x = blockIdx.x;
    int t5 = (x & 7) * 32 + (x >> 3);
    int by = t5 >> 4, bx = t5 & 15;
    const int brow = by * 256, bcol = bx * 256;

    const int wv = tid >> 6, lane = tid & 63;
    const int wm = wv >> 2, wn = wv & 3;     // wave grid 2(M) x 4(N), tile 128x64
    const int r0 = lane & 15, kc = lane >> 4;

    const size_t apan = (size_t)(b * NPAN + by) * NKB * PAGE;
    const size_t bpan = (size_t)(b * NPAN + bx) * NKB * PAGE;

    if (tid < 256) { rowSlot[tid] = ~0ULL; colSlot[tid] = ~0ULL; }

    int aoff[8], boff[4];
#pragma unroll
    for (int m = 0; m < 8; ++m) aoff[m] = swz(wm * 128 + m * 16 + r0, kc * 16);
#pragma unroll
    for (int n = 0; n < 4; ++n) boff[n] = swz(wn * 64 + n * 16 + r0, kc * 16);

    f32x4 acc[8][4];
    f32x4 zero = {0.f, 0.f, 0.f, 0.f};
#pragma unroll
    for (int m = 0; m < 8; ++m)
#pragma unroll
        for (int n = 0; n < 4; ++n) acc[m][n] = zero;

    char* buf0 = smem;                 // compute (step s)
    char* buf1 = smem + 2 * PAGE;      // next (step s+1, loads in flight)
    char* buf2 = smem + 4 * PAGE;      // staging target (step s+2)
    const int wchunk = wv * 1024;          // wave-uniform LDS chunk
    const int gchunk = wchunk + lane * 16; // per-lane global offset

    auto pageptrs = [&](int s, const char*& Ap, const char*& Bp) {
        int sweep = (s >= 24) ? 2 : ((s >= 12) ? 1 : 0);
        int kb = s - sweep * 12;
        const char* Asel = (sweep == 0) ? tAlo : tAhi;   // sweep0: lo_A . hi_B
        const char* Bsel = (sweep == 1) ? tBlo : tBhi;   // sweep1: hi_A . lo_B
        Ap = Asel + apan + (size_t)kb * PAGE;
        Bp = Bsel + bpan + (size_t)kb * PAGE;
    };

    // prologue: stage steps 0 and 1
    {
        const char *Ap, *Bp;
        pageptrs(0, Ap, Bp);
        gl_lds16(Ap + gchunk, buf0 + wchunk);
        gl_lds16(Ap + 8192 + gchunk, buf0 + 8192 + wchunk);
        gl_lds16(Bp + gchunk, buf0 + PAGE + wchunk);
        gl_lds16(Bp + 8192 + gchunk, buf0 + PAGE + 8192 + wchunk);
        pageptrs(1, Ap, Bp);
        gl_lds16(Ap + gchunk, buf1 + wchunk);
        gl_lds16(Ap + 8192 + gchunk, buf1 + 8192 + wchunk);
        gl_lds16(Bp + gchunk, buf1 + PAGE + wchunk);
        gl_lds16(Bp + 8192 + gchunk, buf1 + PAGE + 8192 + wchunk);
    }
    asm volatile("s_waitcnt vmcnt(4)" ::: "memory");   // step 0 done, step 1 in flight
    BAR();

#pragma unroll 1
    for (int s = 0; s < NSTEP; ++s) {
        const char *ApN = nullptr, *BpN = nullptr;
        const bool st = (s + 2 < NSTEP);
        if (st) pageptrs(s + 2, ApN, BpN);

        // ---- phase 0: b-frags + a-frags 0..3, stage A(s+2), 16 MFMA
        f16x8 bfr[4], afr[4];
#pragma unroll
        for (int n = 0; n < 4; ++n) bfr[n] = *(const f16x8*)(buf0 + PAGE + boff[n]);
#pragma unroll
        for (int m = 0; m < 4; ++m) afr[m] = *(const f16x8*)(buf0 + aoff[m]);
        if (st) {
            gl_lds16(ApN + gchunk, buf2 + wchunk);
            gl_lds16(ApN + 8192 + gchunk, buf2 + 8192 + wchunk);
        }
        BAR();
        __builtin_amdgcn_s_setprio(1);
#pragma unroll
        for (int m = 0; m < 4; ++m)
#pragma unroll
            for (int n = 0; n < 4; ++n)
                acc[m][n] = __builtin_amdgcn_mfma_f32_16x16x32_f16(afr[m], bfr[n], acc[m][n], 0, 0, 0);
        __builtin_amdgcn_s_setprio(0);
        BAR();

        // ---- phase 1: a-frags 4..7, stage B(s+2), 16 MFMA
        f16x8 afr2[4];
#pragma unroll
        for (int m = 0; m < 4; ++m) afr2[m] = *(const f16x8*)(buf0 + aoff[m + 4]);
        if (st) {
            gl_lds16(BpN + gchunk, buf2 + PAGE + wchunk);
            gl_lds16(BpN + 8192 + gchunk, buf2 + PAGE + 8192 + wchunk);
        }
        BAR();
        __builtin_amdgcn_s_setprio(1);
#pragma unroll
        for (int m = 0; m < 4; ++m)
#pragma unroll
            for (int n = 0; n < 4; ++n)
                acc[m + 4][n] = __builtin_amdgcn_mfma_f32_16x16x32_f16(afr2[m], bfr[n], acc[m + 4][n], 0, 0, 0);
        __builtin_amdgcn_s_setprio(0);

        // end of BOTH cross sweeps (lo.hi steps 0-11, hi.lo steps 12-23):
        // rescale the 2048-scaled cross sum before the unit-scale hi.hi sweep.
        if (s == 23) {
#pragma unroll
            for (int m = 0; m < 8; ++m)
#pragma unroll
                for (int n = 0; n < 4; ++n)
                    acc[m][n] *= (1.0f / 2048.0f);
        }

        // counted wait: step s+1's 4 loads done; step s+2's 4 stay in flight
        if (s < NSTEP - 2) asm volatile("s_waitcnt vmcnt(4)" ::: "memory");
        else               asm volatile("s_waitcnt vmcnt(0)" ::: "memory");
        BAR();

        char* tmp = buf0; buf0 = buf1; buf1 = buf2; buf2 = tmp;
    }

    // ---------------- epilogue: d + row/col argmin (u64-encoded, shuffle-reduced)
    const size_t bb = (size_t)b * HW;
    u64 cbest[4] = {~0ULL, ~0ULL, ~0ULL, ~0ULL};
    float s2v[4];
    int m2v[4];
#pragma unroll
    for (int n = 0; n < 4; ++n) {
        int cc = bcol + wn * 64 + n * 16 + r0;
        s2v[n] = sq2[bb + cc];
        m2v[n] = mask2[bb + cc];
    }
#pragma unroll
    for (int m = 0; m < 8; ++m) {
        int rbase = brow + wm * 128 + m * 16 + kc * 4;
        float4 sv = *(const float4*)(sq1 + bb + rbase);
        int4 mv = *(const int4*)(mask1 + bb + rbase);
        float s1a[4] = {sv.x, sv.y, sv.z, sv.w};
        int m1a[4] = {mv.x, mv.y, mv.z, mv.w};
#pragma unroll
        for (int j = 0; j < 4; ++j) {
            u64 rbest = ~0ULL;
            int rr = rbase + j;
#pragma unroll
            for (int n = 0; n < 4; ++n) {
                float dot = acc[m][n][j];
                float d;
                if (m1a[j] && m2v[n]) {
                    float t2 = __fmul_rn(2.0f, dot);
                    float d2 = __fsub_rn(__fadd_rn(s1a[j], s2v[n]), t2);
                    d = __fsqrt_rn(fmaxf(d2, 0.0f));
                } else {
                    d = BIG_DIST;
                }
                int cc = bcol + wn * 64 + n * 16 + r0;
                u64 er = encode_di(d, cc);
                u64 ec = encode_di(d, rr);
                if (er < rbest) rbest = er;
                if (ec < cbest[n]) cbest[n] = ec;
            }
            rbest = min_shfl(rbest, 1);
            rbest = min_shfl(rbest, 2);
            rbest = min_shfl(rbest, 4);
            rbest = min_shfl(rbest, 8);
            if (r0 == 0) atomicMin(&rowSlot[wm * 128 + m * 16 + kc * 4 + j], rbest);
        }
    }
#pragma unroll
    for (int n = 0; n < 4; ++n) {
        u64 v = cbest[n];
        v = min_shfl(v, 16);
        v = min_shfl(v, 32);
        if (kc == 0) atomicMin(&colSlot[wn * 64 + n * 16 + r0], v);
    }
    __syncthreads();

    if (tid < 256) atomicMin(&slot1[bb + brow + tid], rowSlot[tid]);
    else           atomicMin(&slot2[bb + bcol + tid - 256], colSlot[tid - 256]);
}

// ------------------------------------------------------------ extract matches
__global__ void extract_matches(const u64* __restrict__ slot1,
                                const u64* __restrict__ slot2,
                                int* __restrict__ match1, int* __restrict__ match2,
                                int n) {
    int i = blockIdx.x * blockDim.x + threadIdx.x;
    if (i < n) {
        match1[i] = (int)(unsigned)(slot1[i] & 0xFFFFFFFFu);
        match2[i] = (int)(unsigned)(slot2[i] & 0xFFFFFFFFu);
    }
}

// -------------------------------------------------------- cyclic coord keys
__global__ void compute_keys(const int* __restrict__ match1,
                             const int* __restrict__ match2,
                             const int* __restrict__ mask1,
                             const int* __restrict__ mask2,
                             u64* __restrict__ key1, u64* __restrict__ key2) {
    int g = blockIdx.x * blockDim.x + threadIdx.x;
    if (g >= NB * HW) return;
    int i = g & (HW - 1);
    int base = g - i;
    float gx = (float)(i >> 6), gy = (float)(i & 63);
    {
        int mf = match1[g];
        int dst_valid = mask2[base + mf];
        int cyc = match2[base + mf];
        float dx = (float)(cyc >> 6) - gx;
        float dy = (float)(cyc & 63) - gy;
        float diff = __fsqrt_rn(dx * dx + dy * dy);
        float v = ((mask1[g] > 0) && (dst_valid > 0)) ? diff : BIG_DIFF;
        key1[g] = encode_di(v, i);
    }
    {
        int mf = match2[g];
        int dst_valid = mask1[base + mf];
        int cyc = match1[base + mf];
        float dx = (float)(cyc >> 6) - gx;
        float dy = (float)(cyc & 63) - gy;
        float diff = __fsqrt_rn(dx * dx + dy * dy);
        float v = ((mask2[g] > 0) && (dst_valid > 0)) ? diff : BIG_DIFF;
        key2[g] = encode_di(v, i);
    }
}

// ----------------------------------------------- top-K via LDS bitonic sort
__global__ __launch_bounds__(1024)
void topk_output(const u64* __restrict__ key1, const u64* __restrict__ key2,
                 const int* __restrict__ match1, const int* __restrict__ match2,
                 const int* __restrict__ mask1, const int* __restrict__ mask2,
                 const int* __restrict__ backup1, const int* __restrict__ backup2,
                 int* __restrict__ out) {
    __shared__ u64 keys[HW];
    __shared__ int cnt;
    const int b = blockIdx.x;
    const int dir = blockIdx.y;
    const u64* key = dir ? key2 : key1;
    const int* match = dir ? match2 : match1;
    const int* mask = dir ? mask2 : mask1;
    const int* backup = dir ? backup2 : backup1;
    const int tid = threadIdx.x;
    const size_t base = (size_t)b * HW;

    if (tid == 0) cnt = 0;
    __syncthreads();
    int local = 0;
    for (int t = tid; t < HW; t += 1024) {
        keys[t] = key[base + t];
        local += (mask[base + t] > 0) ? 1 : 0;
    }
    atomicAdd(&cnt, local);
    __syncthreads();

    for (unsigned k = 2; k <= HW; k <<= 1) {
        for (unsigned j = k >> 1; j > 0; j >>= 1) {
            for (unsigned t = tid; t < HW; t += 1024) {
                unsigned ixj = t ^ j;
                if (ixj > t) {
                    u64 a = keys[t], c = keys[ixj];
                    bool up = ((t & k) == 0);
                    if ((a > c) == up) { keys[t] = c; keys[ixj] = a; }
                }
            }
            __syncthreads();
        }
    }

    if (tid < K_SEL) {
        int c;
        if (cnt >= K_SEL) c = (int)(unsigned)(keys[tid] & 0xFFFFFFFFu);
        else c = backup[b * K_SEL + tid];
        int cm = match[base + c];
        int* o = out + dir * (NB * K_SEL * 2);
        o[(b * K_SEL + tid) * 2 + 0] = c;
        o[(b * K_SEL + tid) * 2 + 1] = cm;
    }
}

// ---------------------------------------------------------------------------
extern "C" void kernel_launch(void* const* d_in, const int* in_sizes, int n_in,
                              void* d_out, int out_size, void* d_ws, size_t ws_size,
                              hipStream_t stream) {
    const float* f1 = (const float*)d_in[0];
    const float* f2 = (const float*)d_in[1];
    const int* mask1 = (const int*)d_in[2];
    const int* mask2 = (const int*)d_in[3];
    const int* backup1 = (const int*)d_in[4];
    const int* backup2 = (const int*)d_in[5];
    int* out = (int*)d_out;

    const size_t TSZ = (size_t)NB * NPAN * NKB * PAGE;   // 24 MiB per tile array
    char* ws = (char*)d_ws;
    char* tAhi = ws;  ws += TSZ;
    char* tAlo = ws;  ws += TSZ;
    char* tBhi = ws;  ws += TSZ;
    char* tBlo = ws;  ws += TSZ;
    u64* slot1 = (u64*)ws;            ws += (size_t)NB * HW * 8;
    u64* slot2 = (u64*)ws;            ws += (size_t)NB * HW * 8;
    u64* key1 = (u64*)ws;             ws += (size_t)NB * HW * 8;
    u64* key2 = (u64*)ws;             ws += (size_t)NB * HW * 8;
    float* rn1 = (float*)ws;          ws += (size_t)NB * HW * 4;
    float* rn2 = (float*)ws;          ws += (size_t)NB * HW * 4;
    float* sq1 = (float*)ws;          ws += (size_t)NB * HW * 4;
    float* sq2 = (float*)ws;          ws += (size_t)NB * HW * 4;
    int* match1 = (int*)ws;           ws += (size_t)NB * HW * 4;
    int* match2 = (int*)ws;           ws += (size_t)NB * HW * 4;

    const int nrows = NB * HW;

    init_slots<<<(2 * nrows + 255) / 256, 256, 0, stream>>>(slot1, 2 * nrows);
    normalize_rows<<<(2 * nrows) / 4, 256, 0, stream>>>(f1, f2, mask1, mask2,
                                                        rn1, rn2, sq1, sq2);
    convert_tiles<<<dim3(NB * NPAN * NKB, 2), 256, 0, stream>>>(f1, f2, rn1, rn2,
                                                                tAhi, tAlo, tBhi, tBlo);
    gemm_argmin<<<dim3(256, NB), 512, 0, stream>>>(tAhi, tAlo, tBhi, tBlo,
                                                   mask1, mask2, sq1, sq2,
                                                   slot1, slot2);
    extract_matches<<<(nrows + 255) / 256, 256, 0, stream>>>(slot1, slot2,
                                                             match1, match2, nrows);
    compute_keys<<<(nrows + 255) / 256, 256, 0, stream>>>(match1, match2,
                                                          mask1, mask2, key1, key2);
    topk_output<<<dim3(NB, 2), 1024, 0, stream>>>(key1, key2, match1, match2,
                                                  mask1, mask2, backup1, backup2,
                                                  out);
}